// Round 3
// baseline (376.579 us; speedup 1.0000x reference)
//
#include <hip/hip_runtime.h>
#include <stdint.h>

#define EFFECT_DIM 758
#define ADD_DIM 10
#define EMBED_DIM 768
#define NCOLS 95000
#define NSYN 8
#define NROWS 1024
#define NTILE_N 743   // ceil(95000/128)

typedef __attribute__((ext_vector_type(8))) __bf16 bf16x8;
typedef __attribute__((ext_vector_type(16))) float f32x16;
typedef __attribute__((ext_vector_type(4))) uint32_t u32x4;

// single-instruction f32 pair -> packed bf16 (RNE)
static __device__ __forceinline__ uint32_t pack2(float a, float b) {
  uint32_t r;
  asm("v_cvt_pk_bf16_f32 %0, %1, %2" : "=v"(r) : "v"(a), "v"(b));
  return r;
}

#define GLOAD16(src, dst)                                                   \
  __builtin_amdgcn_global_load_lds(                                         \
      (const __attribute__((address_space(1))) uint32_t*)(src),             \
      (__attribute__((address_space(3))) uint32_t*)(dst), 16, 0, 0)

// ---------------------------------------------------------------------------
// Kernel 1: VirtualEmbedding -> bf16 A tiles at ws[0..1.5MB).
// tile(mt, ks) at (mt*12+ks)*16384 bytes, [128 rows][64 k] bf16,
// swizzled: byte(r, c2) = r*128 + (c2 ^ ((r&7)<<4)).
// ---------------------------------------------------------------------------
__global__ __launch_bounds__(256) void emb_kernel(
    const int* __restrict__ ids, const float* __restrict__ W_emb,
    const float* __restrict__ padding, const int* __restrict__ syn_table,
    const int* __restrict__ syn_mask, char* __restrict__ ws)
{
  const int l = blockIdx.x;
  const int t = threadIdx.x;
  const int id = ids[l];
  int sid[NSYN];
  int msk[NSYN];
#pragma unroll
  for (int k = 0; k < NSYN; ++k) {
    sid[k] = syn_table[id * NSYN + k];
    msk[k] = syn_mask[id * NSYN + k];
  }

  double p[9] = {0, 0, 0, 0, 0, 0, 0, 0, 0};
  for (int d = t; d < EFFECT_DIM; d += 256) {
    p[0] += (double)W_emb[(size_t)id * EFFECT_DIM + d];
#pragma unroll
    for (int k = 0; k < NSYN; ++k)
      p[k + 1] += (double)W_emb[(size_t)sid[k] * EFFECT_DIM + d];
  }

  __shared__ double s_red[9][4];
  const int w = t >> 6;
#pragma unroll
  for (int k = 0; k < 9; ++k) {
    double v = p[k];
#pragma unroll
    for (int off = 32; off > 0; off >>= 1) v += __shfl_down(v, off, 64);
    if ((t & 63) == 0) s_red[k][w] = v;
  }
  __syncthreads();

  const double isum = s_red[0][0] + s_red[0][1] + s_red[0][2] + s_red[0][3];
  float coef[NSYN];
#pragma unroll
  for (int k = 0; k < NSYN; ++k) {
    double ss = s_red[k + 1][0] + s_red[k + 1][1] + s_red[k + 1][2] + s_red[k + 1][3];
    coef[k] = msk[k] ? (float)(isum / ss) : 0.0f;
  }

  const int mt = l >> 7;
  const int r  = l & 127;
  const int sw = (r & 7) << 4;
  char* wbase = ws + (size_t)mt * (12 * 16384);

  for (int j = t; j < 384; j += 256) {
    const int d0 = 2 * j;
    float v0, v1;
    if (d0 < EFFECT_DIM) {
      const float* bp = W_emb + (size_t)id * EFFECT_DIM + d0;
      v0 = bp[0];
      v1 = bp[1];
#pragma unroll
      for (int k = 0; k < NSYN; ++k) {
        const float* sp = W_emb + (size_t)sid[k] * EFFECT_DIM + d0;
        v0 = fmaf(coef[k], sp[0], v0);
        v1 = fmaf(coef[k], sp[1], v1);
      }
    } else {
      v0 = padding[l * ADD_DIM + (d0 - EFFECT_DIM)];
      v1 = padding[l * ADD_DIM + (d0 + 1 - EFFECT_DIM)];
    }
    const int ks = j >> 5;
    const int jl = j & 31;
    *(uint32_t*)(wbase + ks * 16384 + r * 128 + ((jl * 4) ^ sw)) = pack2(v0, v1);
  }
}

// ---------------------------------------------------------------------------
// Kernel 1b: W_rev f32 [768][95000] -> bf16 [n][k] swizzled tiles.
// tile(nt, ks) at (nt*12+ks)*16384, [128 n-rows][64 k] bf16, same swizzle.
// ---------------------------------------------------------------------------
__global__ __launch_bounds__(256) void conv_kernel(
    const float* __restrict__ Wrev, char* __restrict__ Bbuf)
{
  __shared__ char lds[16384];
  const int t  = threadIdx.x;
  const int nt = blockIdx.x;
  const int ks = blockIdx.y;

  const int nl = t & 127;
  const int kc_base = t >> 7;  // 0 or 1
  const int gn = nt * 128 + nl;
  const bool valid = gn < NCOLS;
  const int sw = (nl & 7) << 4;

#pragma unroll
  for (int task = 0; task < 4; ++task) {
    const int kc = kc_base + task * 2;  // 0..7 (8-k chunk)
    float v[8];
    const float* p = Wrev + (size_t)(ks * 64 + kc * 8) * NCOLS + gn;
#pragma unroll
    for (int j = 0; j < 8; ++j)
      v[j] = valid ? p[(size_t)j * NCOLS] : 0.0f;
    u32x4 u;
#pragma unroll
    for (int j = 0; j < 4; ++j)
      u[j] = pack2(v[2 * j], v[2 * j + 1]);
    *(u32x4*)(lds + nl * 128 + ((kc * 16) ^ sw)) = u;
  }
  __syncthreads();

  char* dst = Bbuf + (size_t)(nt * 12 + ks) * 16384;
#pragma unroll
  for (int i = 0; i < 4; ++i)
    *(u32x4*)(dst + t * 16 + i * 4096) = *(const u32x4*)(lds + t * 16 + i * 4096);
}

// ---------------------------------------------------------------------------
// Kernel 2: XCD-swizzled grid + 2-phase double-buffered pipeline.
// Per K-step: prefetch next tile (8x global_load_lds), counted vmcnt(8)
// (never 0 mid-loop), raw s_barrier, swizzled ds_read_b128, 16x MFMA.
// ---------------------------------------------------------------------------
__global__ __launch_bounds__(256, 2) void gemm_pre(
    const char* __restrict__ Abuf, const char* __restrict__ Bbuf,
    float* __restrict__ out)
{
  __shared__ char lds[65536];  // two 32KB buffers (A:16K + B:16K each)
  const int t  = threadIdx.x;
  const int l  = t & 63;
  const int w  = t >> 6;
  const int wm = w >> 1;
  const int wn = w & 1;
  const int lr = l & 31;
  const int lh = l >> 5;

  // XCD-aware remap: 5944 = 8 XCDs x 743 blocks. Each XCD owns a contiguous
  // chunk of (nt, mt) work with mt fastest -> the 8 blocks sharing a B panel
  // co-reside on one XCD's L2.
  const int wgid = blockIdx.x;
  const int xcd  = wgid & 7;
  const int work = xcd * 743 + (wgid >> 3);
  const int mt = work & 7;
  const int nt = work >> 3;
  const int n0 = nt * 128;

  f32x16 acc[2][2] = {};

  const char* asrc = Abuf + (size_t)mt * (12 * 16384);
  const char* bsrc = Bbuf + (size_t)nt * (12 * 16384);
  const int soff = w * 1024 + l * 16;

#define STAGE(buf, ksi)                                                      \
  {                                                                          \
    const char* sa = asrc + (ksi)*16384 + soff;                              \
    const char* sb = bsrc + (ksi)*16384 + soff;                              \
    char* da = lds + (buf)*32768 + w * 1024;                                 \
    char* db = lds + (buf)*32768 + 16384 + w * 1024;                         \
    _Pragma("unroll") for (int i = 0; i < 4; ++i) {                          \
      GLOAD16(sa + i * 4096, da + i * 4096);                                 \
      GLOAD16(sb + i * 4096, db + i * 4096);                                 \
    }                                                                        \
  }

  STAGE(0, 0);

  for (int ks = 0; ks < 12; ++ks) {
    if (ks < 11) {
      STAGE((ks + 1) & 1, ks + 1);
      asm volatile("s_waitcnt vmcnt(8)");  // current tile's 8 loads done
    } else {
      asm volatile("s_waitcnt vmcnt(0)");
    }
    __builtin_amdgcn_sched_barrier(0);
    __builtin_amdgcn_s_barrier();

    const char* base = lds + (ks & 1) * 32768;

    bf16x8 af[2][4], bg[2][4];
#pragma unroll
    for (int mr = 0; mr < 2; ++mr) {
      const int rr = wm * 64 + mr * 32 + lr;
      const int swz = (rr & 7) << 4;
#pragma unroll
      for (int kk = 0; kk < 4; ++kk) {
        const int c2 = kk * 32 + lh * 16;
        af[mr][kk] = *(const bf16x8*)(base + rr * 128 + (c2 ^ swz));
      }
    }
#pragma unroll
    for (int nr = 0; nr < 2; ++nr) {
      const int rr = wn * 64 + nr * 32 + lr;
      const int swz = (rr & 7) << 4;
#pragma unroll
      for (int kk = 0; kk < 4; ++kk) {
        const int c2 = kk * 32 + lh * 16;
        bg[nr][kk] = *(const bf16x8*)(base + 16384 + rr * 128 + (c2 ^ swz));
      }
    }
    __builtin_amdgcn_s_setprio(1);
#pragma unroll
    for (int kk = 0; kk < 4; ++kk)
#pragma unroll
      for (int mr = 0; mr < 2; ++mr)
#pragma unroll
        for (int nr = 0; nr < 2; ++nr)
          acc[mr][nr] = __builtin_amdgcn_mfma_f32_32x32x16_bf16(
              af[mr][kk], bg[nr][kk], acc[mr][nr], 0, 0, 0);
    __builtin_amdgcn_s_setprio(0);
    __builtin_amdgcn_s_barrier();  // all waves done reading buf[ks&1]
  }
#undef STAGE

#pragma unroll
  for (int mr = 0; mr < 2; ++mr)
#pragma unroll
    for (int nr = 0; nr < 2; ++nr) {
      const int gc = n0 + wn * 64 + nr * 32 + lr;
      if (gc < NCOLS) {
#pragma unroll
        for (int reg = 0; reg < 16; ++reg) {
          const int row = (reg & 3) + 8 * (reg >> 2) + 4 * lh;
          const int gr = mt * 128 + wm * 64 + mr * 32 + row;
          out[(size_t)gr * NCOLS + gc] = acc[mr][nr][reg];
        }
      }
    }
}

// ---------------------------------------------------------------------------
// Fallback GEMM (ws too small): round-1 structure, cvt_pk pack.
// ---------------------------------------------------------------------------
__global__ __launch_bounds__(256, 2) void gemm_kernel(
    const float* __restrict__ Wrev, const char* __restrict__ Abuf,
    float* __restrict__ out)
{
  __shared__ char lds[32768];
  const int t  = threadIdx.x;
  const int l  = t & 63;
  const int w  = t >> 6;
  const int wm = w >> 1;
  const int wn = w & 1;
  const int lr = l & 31;
  const int lh = l >> 5;
  const int mt = blockIdx.x;
  const int n0 = blockIdx.y * 128;

  f32x16 acc[2][2] = {};

  const char* asrc = Abuf + (size_t)mt * (12 * 16384);
  const int nl = t & 127;
  const int kc_base = t >> 7;
  const int gn = n0 + nl;
  const int bswz = (nl & 7) << 4;

  for (int ks = 0; ks < 12; ++ks) {
    {
      const char* s = asrc + ks * 16384 + w * 1024 + l * 16;
      char* d = lds + w * 1024;
#pragma unroll
      for (int i = 0; i < 4; ++i)
        GLOAD16(s + i * 4096, d + i * 4096);
    }
#pragma unroll
    for (int task = 0; task < 4; ++task) {
      const int kc = kc_base + task * 2;
      float v[8];
      const float* p = Wrev + (size_t)(ks * 64 + kc * 8) * NCOLS + gn;
#pragma unroll
      for (int j = 0; j < 8; ++j)
        v[j] = (gn < NCOLS) ? p[(size_t)j * NCOLS] : 0.0f;
      u32x4 u;
#pragma unroll
      for (int j = 0; j < 4; ++j)
        u[j] = pack2(v[2 * j], v[2 * j + 1]);
      *(u32x4*)(lds + 16384 + nl * 128 + ((kc * 16) ^ bswz)) = u;
    }
    __syncthreads();

    bf16x8 af[2][4], bg[2][4];
#pragma unroll
    for (int mr = 0; mr < 2; ++mr) {
      const int rr = wm * 64 + mr * 32 + lr;
      const int swz = (rr & 7) << 4;
#pragma unroll
      for (int kk = 0; kk < 4; ++kk) {
        const int c2 = kk * 32 + lh * 16;
        af[mr][kk] = *(const bf16x8*)(lds + rr * 128 + (c2 ^ swz));
      }
    }
#pragma unroll
    for (int nr = 0; nr < 2; ++nr) {
      const int rr = wn * 64 + nr * 32 + lr;
      const int swz = (rr & 7) << 4;
#pragma unroll
      for (int kk = 0; kk < 4; ++kk) {
        const int c2 = kk * 32 + lh * 16;
        bg[nr][kk] = *(const bf16x8*)(lds + 16384 + rr * 128 + (c2 ^ swz));
      }
    }
#pragma unroll
    for (int kk = 0; kk < 4; ++kk)
#pragma unroll
      for (int mr = 0; mr < 2; ++mr)
#pragma unroll
        for (int nr = 0; nr < 2; ++nr)
          acc[mr][nr] = __builtin_amdgcn_mfma_f32_32x32x16_bf16(
              af[mr][kk], bg[nr][kk], acc[mr][nr], 0, 0, 0);
    __syncthreads();
  }

#pragma unroll
  for (int mr = 0; mr < 2; ++mr)
#pragma unroll
    for (int nr = 0; nr < 2; ++nr) {
      const int gc = n0 + wn * 64 + nr * 32 + lr;
      if (gc < NCOLS) {
#pragma unroll
        for (int reg = 0; reg < 16; ++reg) {
          const int row = (reg & 3) + 8 * (reg >> 2) + 4 * lh;
          const int gr = mt * 128 + wm * 64 + mr * 32 + row;
          out[(size_t)gr * NCOLS + gc] = acc[mr][nr][reg];
        }
      }
    }
}

extern "C" void kernel_launch(void* const* d_in, const int* in_sizes, int n_in,
                              void* d_out, int out_size, void* d_ws, size_t ws_size,
                              hipStream_t stream) {
  const int*   ids       = (const int*)d_in[0];
  const float* W_emb     = (const float*)d_in[1];
  const float* W_rev     = (const float*)d_in[2];
  const float* padding   = (const float*)d_in[3];
  const int*   syn_table = (const int*)d_in[4];
  const int*   syn_mask  = (const int*)d_in[5];
  float* out = (float*)d_out;
  char*  ws  = (char*)d_ws;

  const size_t A_BYTES = (size_t)8 * 12 * 16384;            // 1.5 MB
  const size_t B_BYTES = (size_t)NTILE_N * 12 * 16384;      // ~146 MB

  hipLaunchKernelGGL(emb_kernel, dim3(NROWS), dim3(256), 0, stream,
                     ids, W_emb, padding, syn_table, syn_mask, ws);

  if (ws_size >= A_BYTES + B_BYTES) {
    char* Bbuf = ws + A_BYTES;
    hipLaunchKernelGGL(conv_kernel, dim3(NTILE_N, 12), dim3(256), 0, stream,
                       W_rev, Bbuf);
    hipLaunchKernelGGL(gemm_pre, dim3(8 * NTILE_N), dim3(256), 0, stream,
                       ws, Bbuf, out);
  } else {
    hipLaunchKernelGGL(gemm_kernel, dim3(8, NTILE_N), dim3(256), 0, stream,
                       W_rev, ws, out);
  }
}

// Round 4
// 373.855 us; speedup vs baseline: 1.0073x; 1.0073x over previous
//
#include <hip/hip_runtime.h>
#include <stdint.h>

#define EFFECT_DIM 758
#define ADD_DIM 10
#define EMBED_DIM 768
#define NCOLS 95000
#define NSYN 8
#define NROWS 1024
#define NTILE_N 743   // ceil(95000/128)

typedef __attribute__((ext_vector_type(8))) __bf16 bf16x8;
typedef __attribute__((ext_vector_type(16))) float f32x16;
typedef __attribute__((ext_vector_type(4))) uint32_t u32x4;

// single-instruction f32 pair -> packed bf16 (RNE)
static __device__ __forceinline__ uint32_t pack2(float a, float b) {
  uint32_t r;
  asm("v_cvt_pk_bf16_f32 %0, %1, %2" : "=v"(r) : "v"(a), "v"(b));
  return r;
}

#define GLOAD16(src, dst)                                                   \
  __builtin_amdgcn_global_load_lds(                                         \
      (const __attribute__((address_space(1))) uint32_t*)(src),             \
      (__attribute__((address_space(3))) uint32_t*)(dst), 16, 0, 0)

// ---------------------------------------------------------------------------
// Kernel 1: VirtualEmbedding -> bf16 A tiles at ws[0..1.5MB).
// tile(mt, ks) at (mt*12+ks)*16384 bytes, [128 rows][64 k] bf16,
// swizzled: byte(r, c2) = r*128 + (c2 ^ ((r&7)<<4)).
// ---------------------------------------------------------------------------
__global__ __launch_bounds__(256) void emb_kernel(
    const int* __restrict__ ids, const float* __restrict__ W_emb,
    const float* __restrict__ padding, const int* __restrict__ syn_table,
    const int* __restrict__ syn_mask, char* __restrict__ ws)
{
  const int l = blockIdx.x;
  const int t = threadIdx.x;
  const int id = ids[l];
  int sid[NSYN];
  int msk[NSYN];
#pragma unroll
  for (int k = 0; k < NSYN; ++k) {
    sid[k] = syn_table[id * NSYN + k];
    msk[k] = syn_mask[id * NSYN + k];
  }

  double p[9] = {0, 0, 0, 0, 0, 0, 0, 0, 0};
  for (int d = t; d < EFFECT_DIM; d += 256) {
    p[0] += (double)W_emb[(size_t)id * EFFECT_DIM + d];
#pragma unroll
    for (int k = 0; k < NSYN; ++k)
      p[k + 1] += (double)W_emb[(size_t)sid[k] * EFFECT_DIM + d];
  }

  __shared__ double s_red[9][4];
  const int w = t >> 6;
#pragma unroll
  for (int k = 0; k < 9; ++k) {
    double v = p[k];
#pragma unroll
    for (int off = 32; off > 0; off >>= 1) v += __shfl_down(v, off, 64);
    if ((t & 63) == 0) s_red[k][w] = v;
  }
  __syncthreads();

  const double isum = s_red[0][0] + s_red[0][1] + s_red[0][2] + s_red[0][3];
  float coef[NSYN];
#pragma unroll
  for (int k = 0; k < NSYN; ++k) {
    double ss = s_red[k + 1][0] + s_red[k + 1][1] + s_red[k + 1][2] + s_red[k + 1][3];
    coef[k] = msk[k] ? (float)(isum / ss) : 0.0f;
  }

  const int mt = l >> 7;
  const int r  = l & 127;
  const int sw = (r & 7) << 4;
  char* wbase = ws + (size_t)mt * (12 * 16384);

  for (int j = t; j < 384; j += 256) {
    const int d0 = 2 * j;
    float v0, v1;
    if (d0 < EFFECT_DIM) {
      const float* bp = W_emb + (size_t)id * EFFECT_DIM + d0;
      v0 = bp[0];
      v1 = bp[1];
#pragma unroll
      for (int k = 0; k < NSYN; ++k) {
        const float* sp = W_emb + (size_t)sid[k] * EFFECT_DIM + d0;
        v0 = fmaf(coef[k], sp[0], v0);
        v1 = fmaf(coef[k], sp[1], v1);
      }
    } else {
      v0 = padding[l * ADD_DIM + (d0 - EFFECT_DIM)];
      v1 = padding[l * ADD_DIM + (d0 + 1 - EFFECT_DIM)];
    }
    const int ks = j >> 5;
    const int jl = j & 31;
    *(uint32_t*)(wbase + ks * 16384 + r * 128 + ((jl * 4) ^ sw)) = pack2(v0, v1);
  }
}

// ---------------------------------------------------------------------------
// Kernel 2 (fused): out = A(bf16 tiles in ws) x W_rev(f32, converted inline).
// - T1 XCD remap: the 8 m-blocks sharing a W_rev panel co-reside on one XCD.
// - 32KB single-buffer LDS (occupancy ~3-4 blocks/CU).
// - T14: next K-tile's 32 f32 W_rev values prefetched into regs during
//   current compute; counted s_waitcnt vmcnt(32) so the prefetch stays in
//   flight across the barrier (never drained mid-loop).
// Per K-step: cvt_pk+ds_write B (from regs) | 4x GLOAD16 A | 32x f32 prefetch
//             | vmcnt(32)+lgkmcnt(0) | s_barrier | {4x ds_read_b128 + 4 MFMA}x4
//             | s_barrier
// ---------------------------------------------------------------------------
__global__ __launch_bounds__(256, 3) void gemm_fused(
    const float* __restrict__ Wrev, const char* __restrict__ Abuf,
    float* __restrict__ out)
{
  __shared__ char lds[32768];  // A: [0,16K), B: [16K,32K)
  const int t  = threadIdx.x;
  const int l  = t & 63;
  const int w  = t >> 6;
  const int wm = w >> 1;
  const int wn = w & 1;
  const int lr = l & 31;
  const int lh = l >> 5;

  // XCD-aware remap: 5944 = 8 XCDs x 743. mt fastest within an XCD's chunk.
  const int wgid = blockIdx.x;
  const int xcd  = wgid & 7;
  const int work = xcd * 743 + (wgid >> 3);
  const int mt = work & 7;
  const int nt = work >> 3;
  const int n0 = nt * 128;

  f32x16 acc[2][2] = {};

  const char* asrc = Abuf + (size_t)mt * (12 * 16384);
  const int nl = t & 127;          // n within tile for B staging
  const int kc_base = t >> 7;      // 0 or 1
  const int gn = n0 + nl;
  const bool valid = gn < NCOLS;
  const int bswz = (nl & 7) << 4;
  const int soff = w * 1024 + l * 16;

  float r[4][8];  // staged W_rev f32 for the CURRENT K-tile

#define BLOAD(ksi)                                                           \
  {                                                                          \
    _Pragma("unroll") for (int task = 0; task < 4; ++task) {                 \
      const int kc = kc_base + task * 2;                                     \
      const float* p = Wrev + (size_t)((ksi)*64 + kc * 8) * NCOLS + gn;      \
      _Pragma("unroll") for (int j = 0; j < 8; ++j)                          \
        r[task][j] = valid ? p[(size_t)j * NCOLS] : 0.0f;                    \
    }                                                                        \
  }

  BLOAD(0);

  for (int ks = 0; ks < 12; ++ks) {
    // ---- convert current staged B regs -> LDS (compiler inserts the
    //      progressive vmcnt waits for r as it consumes them) ----
#pragma unroll
    for (int task = 0; task < 4; ++task) {
      const int kc = kc_base + task * 2;
      u32x4 u;
#pragma unroll
      for (int j = 0; j < 4; ++j)
        u[j] = pack2(r[task][2 * j], r[task][2 * j + 1]);
      *(u32x4*)(lds + 16384 + nl * 128 + ((kc * 16) ^ bswz)) = u;
    }
    // ---- A stage: 4x global_load_lds (these 4 are the oldest vm ops) ----
    {
      const char* sa = asrc + ks * 16384 + soff;
      char* da = lds + w * 1024;
#pragma unroll
      for (int i = 0; i < 4; ++i)
        GLOAD16(sa + i * 4096, da + i * 4096);
    }
    // ---- T14 prefetch: issue next tile's 32 f32 loads (stay in flight) ----
    if (ks < 11) {
      BLOAD(ks + 1);
      __builtin_amdgcn_sched_barrier(0);
      asm volatile("s_waitcnt vmcnt(32) lgkmcnt(0)");  // A done, ds_writes done
    } else {
      __builtin_amdgcn_sched_barrier(0);
      asm volatile("s_waitcnt vmcnt(0) lgkmcnt(0)");
    }
    __builtin_amdgcn_sched_barrier(0);
    __builtin_amdgcn_s_barrier();

    // ---- compute: per kk read 4 frags then 4 MFMA (caps live VGPRs) ----
    const int ra0 = wm * 64 + lr,      ra1 = ra0 + 32;
    const int rb0 = wn * 64 + lr,      rb1 = rb0 + 32;
    const int sa0 = (ra0 & 7) << 4,    sa1 = (ra1 & 7) << 4;
    const int sb0 = (rb0 & 7) << 4,    sb1 = (rb1 & 7) << 4;
#pragma unroll
    for (int kk = 0; kk < 4; ++kk) {
      const int c2 = kk * 32 + lh * 16;
      bf16x8 a0 = *(const bf16x8*)(lds + ra0 * 128 + (c2 ^ sa0));
      bf16x8 a1 = *(const bf16x8*)(lds + ra1 * 128 + (c2 ^ sa1));
      bf16x8 b0 = *(const bf16x8*)(lds + 16384 + rb0 * 128 + (c2 ^ sb0));
      bf16x8 b1 = *(const bf16x8*)(lds + 16384 + rb1 * 128 + (c2 ^ sb1));
      __builtin_amdgcn_s_setprio(1);
      acc[0][0] = __builtin_amdgcn_mfma_f32_32x32x16_bf16(a0, b0, acc[0][0], 0, 0, 0);
      acc[0][1] = __builtin_amdgcn_mfma_f32_32x32x16_bf16(a0, b1, acc[0][1], 0, 0, 0);
      acc[1][0] = __builtin_amdgcn_mfma_f32_32x32x16_bf16(a1, b0, acc[1][0], 0, 0, 0);
      acc[1][1] = __builtin_amdgcn_mfma_f32_32x32x16_bf16(a1, b1, acc[1][1], 0, 0, 0);
      __builtin_amdgcn_s_setprio(0);
    }
    if (ks < 11) __builtin_amdgcn_s_barrier();  // all waves done reading LDS
  }
#undef BLOAD

  // ---- epilogue: C layout col=lane&31, row=(reg&3)+8*(reg>>2)+4*(lane>>5) ----
#pragma unroll
  for (int mr = 0; mr < 2; ++mr)
#pragma unroll
    for (int nr = 0; nr < 2; ++nr) {
      const int gc = n0 + wn * 64 + nr * 32 + lr;
      if (gc < NCOLS) {
#pragma unroll
        for (int reg = 0; reg < 16; ++reg) {
          const int row = (reg & 3) + 8 * (reg >> 2) + 4 * lh;
          const int gr = mt * 128 + wm * 64 + mr * 32 + row;
          out[(size_t)gr * NCOLS + gc] = acc[mr][nr][reg];
        }
      }
    }
}

extern "C" void kernel_launch(void* const* d_in, const int* in_sizes, int n_in,
                              void* d_out, int out_size, void* d_ws, size_t ws_size,
                              hipStream_t stream) {
  const int*   ids       = (const int*)d_in[0];
  const float* W_emb     = (const float*)d_in[1];
  const float* W_rev     = (const float*)d_in[2];
  const float* padding   = (const float*)d_in[3];
  const int*   syn_table = (const int*)d_in[4];
  const int*   syn_mask  = (const int*)d_in[5];
  float* out = (float*)d_out;
  char*  ws  = (char*)d_ws;

  hipLaunchKernelGGL(emb_kernel, dim3(NROWS), dim3(256), 0, stream,
                     ids, W_emb, padding, syn_table, syn_mask, ws);

  hipLaunchKernelGGL(gemm_fused, dim3(8 * NTILE_N), dim3(256), 0, stream,
                     W_rev, ws, out);
}

// Round 5
// 356.785 us; speedup vs baseline: 1.0555x; 1.0478x over previous
//
#include <hip/hip_runtime.h>
#include <stdint.h>

#define EFFECT_DIM 758
#define ADD_DIM 10
#define EMBED_DIM 768
#define NCOLS 95000
#define NSYN 8
#define NROWS 1024
#define NTILE_N 743   // ceil(95000/128)

typedef __attribute__((ext_vector_type(8))) __bf16 bf16x8;
typedef __attribute__((ext_vector_type(16))) float f32x16;
typedef __attribute__((ext_vector_type(4))) uint32_t u32x4;

// single-instruction f32 pair -> packed bf16 (RNE)
static __device__ __forceinline__ uint32_t pack2(float a, float b) {
  uint32_t r;
  asm("v_cvt_pk_bf16_f32 %0, %1, %2" : "=v"(r) : "v"(a), "v"(b));
  return r;
}

#define GLOAD16(src, dst)                                                   \
  __builtin_amdgcn_global_load_lds(                                         \
      (const __attribute__((address_space(1))) uint32_t*)(src),             \
      (__attribute__((address_space(3))) uint32_t*)(dst), 16, 0, 0)

// compile-time component select (i must be an unrolled constant)
#define F4C(f, i) ((i) == 0 ? (f).x : (i) == 1 ? (f).y : (i) == 2 ? (f).z : (f).w)

// ---------------------------------------------------------------------------
// Kernel 1: VirtualEmbedding -> bf16 A tiles at ws[0..1.5MB).
// tile(mt, ks) at (mt*12+ks)*16384 bytes, [128 rows][64 k] bf16,
// swizzled: byte(r, c2) = r*128 + (c2 ^ ((r&7)<<4)).
// ---------------------------------------------------------------------------
__global__ __launch_bounds__(256) void emb_kernel(
    const int* __restrict__ ids, const float* __restrict__ W_emb,
    const float* __restrict__ padding, const int* __restrict__ syn_table,
    const int* __restrict__ syn_mask, char* __restrict__ ws)
{
  const int l = blockIdx.x;
  const int t = threadIdx.x;
  const int id = ids[l];
  int sid[NSYN];
  int msk[NSYN];
#pragma unroll
  for (int k = 0; k < NSYN; ++k) {
    sid[k] = syn_table[id * NSYN + k];
    msk[k] = syn_mask[id * NSYN + k];
  }

  double p[9] = {0, 0, 0, 0, 0, 0, 0, 0, 0};
  for (int d = t; d < EFFECT_DIM; d += 256) {
    p[0] += (double)W_emb[(size_t)id * EFFECT_DIM + d];
#pragma unroll
    for (int k = 0; k < NSYN; ++k)
      p[k + 1] += (double)W_emb[(size_t)sid[k] * EFFECT_DIM + d];
  }

  __shared__ double s_red[9][4];
  const int w = t >> 6;
#pragma unroll
  for (int k = 0; k < 9; ++k) {
    double v = p[k];
#pragma unroll
    for (int off = 32; off > 0; off >>= 1) v += __shfl_down(v, off, 64);
    if ((t & 63) == 0) s_red[k][w] = v;
  }
  __syncthreads();

  const double isum = s_red[0][0] + s_red[0][1] + s_red[0][2] + s_red[0][3];
  float coef[NSYN];
#pragma unroll
  for (int k = 0; k < NSYN; ++k) {
    double ss = s_red[k + 1][0] + s_red[k + 1][1] + s_red[k + 1][2] + s_red[k + 1][3];
    coef[k] = msk[k] ? (float)(isum / ss) : 0.0f;
  }

  const int mt = l >> 7;
  const int r  = l & 127;
  const int sw = (r & 7) << 4;
  char* wbase = ws + (size_t)mt * (12 * 16384);

  for (int j = t; j < 384; j += 256) {
    const int d0 = 2 * j;
    float v0, v1;
    if (d0 < EFFECT_DIM) {
      const float* bp = W_emb + (size_t)id * EFFECT_DIM + d0;
      v0 = bp[0];
      v1 = bp[1];
#pragma unroll
      for (int k = 0; k < NSYN; ++k) {
        const float* sp = W_emb + (size_t)sid[k] * EFFECT_DIM + d0;
        v0 = fmaf(coef[k], sp[0], v0);
        v1 = fmaf(coef[k], sp[1], v1);
      }
    } else {
      v0 = padding[l * ADD_DIM + (d0 - EFFECT_DIM)];
      v1 = padding[l * ADD_DIM + (d0 + 1 - EFFECT_DIM)];
    }
    const int ks = j >> 5;
    const int jl = j & 31;
    *(uint32_t*)(wbase + ks * 16384 + r * 128 + ((jl * 4) ^ sw)) = pack2(v0, v1);
  }
}

// ---------------------------------------------------------------------------
// Kernel 1b (v2): W_rev f32 [768][95000] -> bf16 [n][k] swizzled tiles.
// float4 loads (4x fewer VMEM issues than v1); LDS bounce; coalesced stores.
// tile(nt, ks) at (nt*12+ks)*16384, [128 n-rows][64 k] bf16, same swizzle.
// ---------------------------------------------------------------------------
__global__ __launch_bounds__(256) void conv_kernel(
    const float* __restrict__ Wrev, char* __restrict__ Bbuf)
{
  __shared__ char lds[16384];
  const int t   = threadIdx.x;
  const int nt  = blockIdx.x;
  const int ks  = blockIdx.y;
  const int nl4 = t & 31;   // which n-quad (4 consecutive n)
  const int kc  = t >> 5;   // 0..7, owns 8 consecutive k-rows
  const int gn4 = nt * 128 + nl4 * 4;
  const bool valid = (gn4 + 4) <= NCOLS;  // NCOLS % 4 == 0 -> clean boundary

  float4 v[8];
  const float* p = Wrev + (size_t)(ks * 64 + kc * 8) * NCOLS + gn4;
#pragma unroll
  for (int j = 0; j < 8; ++j)
    v[j] = valid ? *(const float4*)(p + (size_t)j * NCOLS)
                 : float4{0.0f, 0.0f, 0.0f, 0.0f};

#pragma unroll
  for (int i = 0; i < 4; ++i) {
    const int n = nl4 * 4 + i;
    u32x4 u;
#pragma unroll
    for (int j2 = 0; j2 < 4; ++j2)
      u[j2] = pack2(F4C(v[2 * j2], i), F4C(v[2 * j2 + 1], i));
    *(u32x4*)(lds + n * 128 + ((kc * 16) ^ ((n & 7) << 4))) = u;
  }
  __syncthreads();

  char* dst = Bbuf + (size_t)(nt * 12 + ks) * 16384;
#pragma unroll
  for (int i = 0; i < 4; ++i)
    *(u32x4*)(dst + t * 16 + i * 4096) = *(const u32x4*)(lds + t * 16 + i * 4096);
}

// ---------------------------------------------------------------------------
// Kernel 2: R2's proven synchronous gemm_pre body (32KB single-buffer,
// 2-barrier loop, occupancy ~4 blocks/CU) + T1 XCD-aware remap so the 8
// m-blocks sharing a B panel co-reside on one XCD's L2.
// ---------------------------------------------------------------------------
__global__ __launch_bounds__(256, 4) void gemm_pre(
    const char* __restrict__ Abuf, const char* __restrict__ Bbuf,
    float* __restrict__ out)
{
  __shared__ char lds[32768];
  const int t  = threadIdx.x;
  const int l  = t & 63;
  const int w  = t >> 6;
  const int wm = w >> 1;
  const int wn = w & 1;
  const int lr = l & 31;
  const int lh = l >> 5;

  // T1: 5944 = 8 XCDs x 743. mt fastest within an XCD's contiguous chunk.
  const int wgid = blockIdx.x;
  const int xcd  = wgid & 7;
  const int work = xcd * 743 + (wgid >> 3);
  const int mt = work & 7;
  const int nt = work >> 3;
  const int n0 = nt * 128;

  f32x16 acc[2][2] = {};

  const char* asrc = Abuf + (size_t)mt * (12 * 16384);
  const char* bsrc = Bbuf + (size_t)nt * (12 * 16384);

  for (int ks = 0; ks < 12; ++ks) {
    {
      const char* sa = asrc + ks * 16384 + w * 1024 + l * 16;
      const char* sb = bsrc + ks * 16384 + w * 1024 + l * 16;
      char* da = lds + w * 1024;
      char* db = lds + 16384 + w * 1024;
#pragma unroll
      for (int i = 0; i < 4; ++i) {
        GLOAD16(sa + i * 4096, da + i * 4096);
        GLOAD16(sb + i * 4096, db + i * 4096);
      }
    }
    __syncthreads();

    bf16x8 af[2][4], bg[2][4];
#pragma unroll
    for (int mr = 0; mr < 2; ++mr) {
      const int rr = wm * 64 + mr * 32 + lr;
      const int swz = (rr & 7) << 4;
#pragma unroll
      for (int kk = 0; kk < 4; ++kk) {
        const int c2 = kk * 32 + lh * 16;
        af[mr][kk] = *(const bf16x8*)(lds + rr * 128 + (c2 ^ swz));
      }
    }
#pragma unroll
    for (int nr = 0; nr < 2; ++nr) {
      const int rr = wn * 64 + nr * 32 + lr;
      const int swz = (rr & 7) << 4;
#pragma unroll
      for (int kk = 0; kk < 4; ++kk) {
        const int c2 = kk * 32 + lh * 16;
        bg[nr][kk] = *(const bf16x8*)(lds + 16384 + rr * 128 + (c2 ^ swz));
      }
    }
#pragma unroll
    for (int kk = 0; kk < 4; ++kk)
#pragma unroll
      for (int mr = 0; mr < 2; ++mr)
#pragma unroll
        for (int nr = 0; nr < 2; ++nr)
          acc[mr][nr] = __builtin_amdgcn_mfma_f32_32x32x16_bf16(
              af[mr][kk], bg[nr][kk], acc[mr][nr], 0, 0, 0);
    __syncthreads();
  }

#pragma unroll
  for (int mr = 0; mr < 2; ++mr)
#pragma unroll
    for (int nr = 0; nr < 2; ++nr) {
      const int gc = n0 + wn * 64 + nr * 32 + lr;
      if (gc < NCOLS) {
#pragma unroll
        for (int reg = 0; reg < 16; ++reg) {
          const int row = (reg & 3) + 8 * (reg >> 2) + 4 * lh;
          const int gr = mt * 128 + wm * 64 + mr * 32 + row;
          out[(size_t)gr * NCOLS + gc] = acc[mr][nr][reg];
        }
      }
    }
}

// ---------------------------------------------------------------------------
// Fallback GEMM (ws too small for Bbuf): round-1 structure, inline convert.
// ---------------------------------------------------------------------------
__global__ __launch_bounds__(256, 2) void gemm_kernel(
    const float* __restrict__ Wrev, const char* __restrict__ Abuf,
    float* __restrict__ out)
{
  __shared__ char lds[32768];
  const int t  = threadIdx.x;
  const int l  = t & 63;
  const int w  = t >> 6;
  const int wm = w >> 1;
  const int wn = w & 1;
  const int lr = l & 31;
  const int lh = l >> 5;
  const int mt = blockIdx.x;
  const int n0 = blockIdx.y * 128;

  f32x16 acc[2][2] = {};

  const char* asrc = Abuf + (size_t)mt * (12 * 16384);
  const int nl = t & 127;
  const int kc_base = t >> 7;
  const int gn = n0 + nl;
  const int bswz = (nl & 7) << 4;

  for (int ks = 0; ks < 12; ++ks) {
    {
      const char* s = asrc + ks * 16384 + w * 1024 + l * 16;
      char* d = lds + w * 1024;
#pragma unroll
      for (int i = 0; i < 4; ++i)
        GLOAD16(s + i * 4096, d + i * 4096);
    }
#pragma unroll
    for (int task = 0; task < 4; ++task) {
      const int kc = kc_base + task * 2;
      float v[8];
      const float* p = Wrev + (size_t)(ks * 64 + kc * 8) * NCOLS + gn;
#pragma unroll
      for (int j = 0; j < 8; ++j)
        v[j] = (gn < NCOLS) ? p[(size_t)j * NCOLS] : 0.0f;
      u32x4 u;
#pragma unroll
      for (int j = 0; j < 4; ++j)
        u[j] = pack2(v[2 * j], v[2 * j + 1]);
      *(u32x4*)(lds + 16384 + nl * 128 + ((kc * 16) ^ bswz)) = u;
    }
    __syncthreads();

    bf16x8 af[2][4], bg[2][4];
#pragma unroll
    for (int mr = 0; mr < 2; ++mr) {
      const int rr = wm * 64 + mr * 32 + lr;
      const int swz = (rr & 7) << 4;
#pragma unroll
      for (int kk = 0; kk < 4; ++kk) {
        const int c2 = kk * 32 + lh * 16;
        af[mr][kk] = *(const bf16x8*)(lds + rr * 128 + (c2 ^ swz));
      }
    }
#pragma unroll
    for (int nr = 0; nr < 2; ++nr) {
      const int rr = wn * 64 + nr * 32 + lr;
      const int swz = (rr & 7) << 4;
#pragma unroll
      for (int kk = 0; kk < 4; ++kk) {
        const int c2 = kk * 32 + lh * 16;
        bg[nr][kk] = *(const bf16x8*)(lds + 16384 + rr * 128 + (c2 ^ swz));
      }
    }
#pragma unroll
    for (int kk = 0; kk < 4; ++kk)
#pragma unroll
      for (int mr = 0; mr < 2; ++mr)
#pragma unroll
        for (int nr = 0; nr < 2; ++nr)
          acc[mr][nr] = __builtin_amdgcn_mfma_f32_32x32x16_bf16(
              af[mr][kk], bg[nr][kk], acc[mr][nr], 0, 0, 0);
    __syncthreads();
  }

#pragma unroll
  for (int mr = 0; mr < 2; ++mr)
#pragma unroll
    for (int nr = 0; nr < 2; ++nr) {
      const int gc = n0 + wn * 64 + nr * 32 + lr;
      if (gc < NCOLS) {
#pragma unroll
        for (int reg = 0; reg < 16; ++reg) {
          const int row = (reg & 3) + 8 * (reg >> 2) + 4 * lh;
          const int gr = mt * 128 + wm * 64 + mr * 32 + row;
          out[(size_t)gr * NCOLS + gc] = acc[mr][nr][reg];
        }
      }
    }
}

extern "C" void kernel_launch(void* const* d_in, const int* in_sizes, int n_in,
                              void* d_out, int out_size, void* d_ws, size_t ws_size,
                              hipStream_t stream) {
  const int*   ids       = (const int*)d_in[0];
  const float* W_emb     = (const float*)d_in[1];
  const float* W_rev     = (const float*)d_in[2];
  const float* padding   = (const float*)d_in[3];
  const int*   syn_table = (const int*)d_in[4];
  const int*   syn_mask  = (const int*)d_in[5];
  float* out = (float*)d_out;
  char*  ws  = (char*)d_ws;

  const size_t A_BYTES = (size_t)8 * 12 * 16384;            // 1.5 MB
  const size_t B_BYTES = (size_t)NTILE_N * 12 * 16384;      // ~146 MB

  hipLaunchKernelGGL(emb_kernel, dim3(NROWS), dim3(256), 0, stream,
                     ids, W_emb, padding, syn_table, syn_mask, ws);

  if (ws_size >= A_BYTES + B_BYTES) {
    char* Bbuf = ws + A_BYTES;
    hipLaunchKernelGGL(conv_kernel, dim3(NTILE_N, 12), dim3(256), 0, stream,
                       W_rev, Bbuf);
    hipLaunchKernelGGL(gemm_pre, dim3(8 * NTILE_N), dim3(256), 0, stream,
                       ws, Bbuf, out);
  } else {
    hipLaunchKernelGGL(gemm_kernel, dim3(8, NTILE_N), dim3(256), 0, stream,
                       W_rev, ws, out);
  }
}